// Round 4
// baseline (118.725 us; speedup 1.0000x reference)
//
#include <hip/hip_runtime.h>

// CoAttention, 3-kernel pipeline. R15 (from R14 115.26us):
//  k_proj  : 512 blocks, even bids = E-tiles (32x64, single K=256 chunk,
//            exp fused), odd bids = U/P-tiles (64x64, 2xK128). U/P GEMM VALU
//            now hides under E-path staging latency (was adding to the
//            issue-bound aff kernel).
//  k_aff   : PURE aff, 512 blocks. Single K=256 LDS chunk (stride 260 keeps
//            2-way-free banks), one barrier. x=1+a*q packed via v_pk_fma_f32
//            (2 FMA/issue). Math order identical to R14.
//  k_final : unchanged structure; f2bf via native cast, float4 rs read.
// f2bf everywhere: (__bf16)x -> compiler emits v_cvt_pk_bf16_f32 pairs (RNE,
// same rounding as old bit-twiddle).
// Budget model: ~88us fixed (2x 268MB harness poison fills) + ~27us ours.

#define NEGC (-1e12f)
#define TWO_LOG2E 2.8853900817779268f
#define LOG2E 1.4426950408889634f
#define N2LOG2E (-2.8853900817779268f)

typedef __attribute__((ext_vector_type(8))) short bf16x8;
typedef __attribute__((ext_vector_type(4))) float f32x4;
typedef __attribute__((ext_vector_type(2))) float f32x2;

__device__ __forceinline__ short f2bf(float x)   // RNE f32->bf16 (native cvt)
{
    return __builtin_bit_cast(short, (__bf16)x);
}

__device__ __forceinline__ f32x2 pk_fma(f32x2 a, f32x2 b, f32x2 c)
{
    f32x2 d;
    asm("v_pk_fma_f32 %0, %1, %2, %3" : "=v"(d) : "v"(a), "v"(b), "v"(c));
    return d;
}

// ---------------------------------------------------------------- k_proj
// even bid: E1/E2 = exp(2*(ctx @ Wh-half + bias)), 32x64 tile, one K chunk.
// odd  bid: U/P projections, 64x64 tile, 2 K chunks (R14 k_mid GEMM path).
__global__ __launch_bounds__(256) void k_proj(
    const float* __restrict__ ctx1, const float* __restrict__ ctx2,
    const float* __restrict__ Wh, const float* __restrict__ bh,
    const float* __restrict__ W12, const float* __restrict__ b12,
    const float* __restrict__ W21, const float* __restrict__ b21,
    const float* __restrict__ mask1, const float* __restrict__ mask2,
    float* __restrict__ E1, float* __restrict__ E2,
    float* __restrict__ P12, float* __restrict__ U1,
    float* __restrict__ P21, float* __restrict__ U2,
    float* __restrict__ p1, float* __restrict__ p2,
    float* __restrict__ S1, float* __restrict__ S2)
{
    __shared__ __align__(16) char smem[50688];

    const int t    = threadIdx.x;
    const int bid  = blockIdx.x;
    const int path = bid & 1;
    const int idx  = bid >> 1;

    const int w    = t >> 6;
    const int lane = t & 63;
    const int quad = lane >> 4;
    const int lr   = lane & 15;

    if (bid == 0) {
        for (int i = t; i < 1024; i += 256) {
            int row = i >> 1, b = i & 1;
            p1[b * 512 + row] = __builtin_amdgcn_exp2f(LOG2E * (1.f - mask1[i]) * NEGC);
            p2[b * 512 + row] = __builtin_amdgcn_exp2f(LOG2E * (1.f - mask2[i]) * NEGC);
            S1[b * 512 + row] = 0.f;
            S2[b * 512 + row] = 0.f;
        }
    }

    if (path == 0) {
        // ---------------- E path: 32x64 tile, single K=256 chunk
        const int g  = idx >> 7;
        const int i7 = idx & 127;
        const int r0 = (i7 & 31) * 32;
        const int n0 = (i7 >> 5) * 64;

        const float* A    = g ? ctx2       : ctx1;
        const float* W    = g ? Wh + 65536 : Wh;
        const float* bias = g ? 0          : bh;
        float*       outp = g ? E2         : E1;

        short* Abf = (short*)smem;            // [32][264]
        short* Bbf = Abf + 32 * 264;          // [64][264]

        #pragma unroll
        for (int i = 0; i < 8; ++i) {                   // A: 32 rows x 256 k
            int slot = i * 256 + t;
            int r = slot >> 6, kq = (slot & 63) << 2;
            float4 v = *(const float4*)(A + (r0 + r) * 256 + kq);
            short4 s; s.x = f2bf(v.x); s.y = f2bf(v.y); s.z = f2bf(v.z); s.w = f2bf(v.w);
            *(short4*)(Abf + r * 264 + kq) = s;
        }
        #pragma unroll
        for (int i = 0; i < 16; ++i) {                  // B: 256 k x 64 n -> B^T
            int slot = i * 256 + t;
            int bk = slot >> 4, bn4 = (slot & 15) << 2;
            float4 v = *(const float4*)(W + bk * 256 + n0 + bn4);
            Bbf[(bn4 + 0) * 264 + bk] = f2bf(v.x);
            Bbf[(bn4 + 1) * 264 + bk] = f2bf(v.y);
            Bbf[(bn4 + 2) * 264 + bk] = f2bf(v.z);
            Bbf[(bn4 + 3) * 264 + bk] = f2bf(v.w);
        }
        __syncthreads();

        const int h = w & 1;                  // row-half
        const int c = w >> 1;                 // col-half

        f32x4 acc[2] = {};

        #pragma unroll
        for (int s = 0; s < 8; ++s) {
            const int kb = s * 32 + quad * 8;
            bf16x8 a = *(const bf16x8*)(Abf + (h * 16 + lr) * 264 + kb);
            #pragma unroll
            for (int nc = 0; nc < 2; ++nc) {
                bf16x8 b = *(const bf16x8*)(Bbf + (c * 32 + nc * 16 + lr) * 264 + kb);
                acc[nc] = __builtin_amdgcn_mfma_f32_16x16x32_bf16(a, b, acc[nc], 0, 0, 0);
            }
        }

        #pragma unroll
        for (int nc = 0; nc < 2; ++nc) {
            const int col = n0 + c * 32 + nc * 16 + lr;
            const float bv = bias ? bias[col] : 0.f;
            #pragma unroll
            for (int reg = 0; reg < 4; ++reg) {
                int row  = r0 + h * 16 + quad * 4 + reg;   // = l*2+b
                int orow = ((row & 1) << 9) + (row >> 1);
                float v = acc[nc][reg] + bv;
                outp[orow * 256 + col] = __builtin_amdgcn_exp2f(v * TWO_LOG2E);
            }
        }
    } else {
        // ---------------- U/P path: 64x64 tile, 2 K chunks
        const int g  = idx >> 6;
        const int r0 = (idx & 15) * 64;
        const int n0 = ((idx >> 4) & 3) * 64;

        const float* A; const float* W; const float* bias; float* outp;
        switch (g) {
          case 0:  A = ctx2; W = W12;         bias = b12; outp = P12; break;
          case 1:  A = ctx1; W = W12 + 65536; bias = 0;   outp = U1;  break;
          case 2:  A = ctx1; W = W21;         bias = b21; outp = P21; break;
          default: A = ctx2; W = W21 + 65536; bias = 0;   outp = U2;  break;
        }

        short* Abf = (short*)smem;            // [64][136]
        short* Bbf = Abf + 64 * 136;          // [64][136]

        f32x4 acc[4] = {};

        for (int kc = 0; kc < 256; kc += 128) {
            #pragma unroll
            for (int i = 0; i < 8; ++i) {             // A: 64 rows x 128 k
                int slot = i * 256 + t;
                int r = slot >> 5, kq = (slot & 31) << 2;
                float4 v = *(const float4*)(A + (r0 + r) * 256 + kc + kq);
                short4 s; s.x = f2bf(v.x); s.y = f2bf(v.y); s.z = f2bf(v.z); s.w = f2bf(v.w);
                *(short4*)(Abf + r * 136 + kq) = s;
            }
            #pragma unroll
            for (int i = 0; i < 8; ++i) {             // B: 128 k x 64 n -> B^T
                int slot = i * 256 + t;
                int bk = slot >> 4, bn4 = (slot & 15) << 2;
                float4 v = *(const float4*)(W + (kc + bk) * 256 + n0 + bn4);
                Bbf[(bn4 + 0) * 136 + bk] = f2bf(v.x);
                Bbf[(bn4 + 1) * 136 + bk] = f2bf(v.y);
                Bbf[(bn4 + 2) * 136 + bk] = f2bf(v.z);
                Bbf[(bn4 + 3) * 136 + bk] = f2bf(v.w);
            }
            __syncthreads();
            #pragma unroll
            for (int s = 0; s < 4; ++s) {
                const int kb = s * 32 + quad * 8;
                bf16x8 a = *(const bf16x8*)(Abf + (w * 16 + lr) * 136 + kb);
                #pragma unroll
                for (int nc = 0; nc < 4; ++nc) {
                    bf16x8 b = *(const bf16x8*)(Bbf + (nc * 16 + lr) * 136 + kb);
                    acc[nc] = __builtin_amdgcn_mfma_f32_16x16x32_bf16(a, b, acc[nc], 0, 0, 0);
                }
            }
            __syncthreads();
        }

        #pragma unroll
        for (int nc = 0; nc < 4; ++nc) {
            const int col = n0 + nc * 16 + lr;
            const float bv = bias ? bias[col] : 0.f;
            #pragma unroll
            for (int reg = 0; reg < 4; ++reg) {
                int row  = r0 + w * 16 + quad * 4 + reg;   // = l*2+b
                int orow = ((row & 1) << 9) + (row >> 1);
                outp[orow * 256 + col] = acc[nc][reg] + bv;
            }
        }
    }
}

// ----------------------------------------------------------------- k_aff
// acc += w.x/x0 + w.y/x1 + w.z/x2 + w.w/x3; x via v_pk_fma_f32, 2 rcp per 4k.
__device__ __forceinline__ void pair4(const float4 AV, const float4 QV,
                                      const float4 WV, const f32x2 one,
                                      float& ACC)
{
    f32x2 alo = {AV.x, AV.y}, ahi = {AV.z, AV.w};
    f32x2 qlo = {QV.x, QV.y}, qhi = {QV.z, QV.w};
    f32x2 x01 = pk_fma(alo, qlo, one);
    f32x2 x23 = pk_fma(ahi, qhi, one);
    float r01 = __builtin_amdgcn_rcpf(x01.x * x01.y);
    float r23 = __builtin_amdgcn_rcpf(x23.x * x23.y);
    float z01 = fmaf(WV.y, x01.x, WV.x * x01.y);
    float z23 = fmaf(WV.w, x23.x, WV.z * x23.y);
    ACC = fmaf(r01, z01, ACC);
    ACC = fmaf(r23, z23, ACC);
}

__global__ __launch_bounds__(256) void k_aff(
    const float* __restrict__ E1g, const float* __restrict__ E2g,
    const float* __restrict__ wo,
    const float* __restrict__ p1g, const float* __restrict__ p2g,
    float* __restrict__ EN, float* __restrict__ ET,
    float* __restrict__ S1, float* __restrict__ S2)
{
    const int t   = threadIdx.x;
    const int bid = blockIdx.x;
    const int l0 = (bid & 15) * 32;
    const int m0 = ((bid >> 4) & 15) * 32;
    const int b  = bid >> 8;

    __shared__ __align__(16) float E1s[32 * 260];   // 33.3 KB, full K
    __shared__ __align__(16) float E2s[32 * 260];   // 33.3 KB
    __shared__ __align__(16) float affs[32 * 36];   //  4.6 KB

    #pragma unroll
    for (int i = 0; i < 8; ++i) {                   // 32 rows x 256 k, both panels
        int slot = i * 256 + t;
        int r = slot >> 6, kq = (slot & 63) << 2;
        *(float4*)(E1s + r * 260 + kq) =
            *(const float4*)(E1g + (((b << 9) + l0 + r) << 8) + kq);
        *(float4*)(E2s + r * 260 + kq) =
            *(const float4*)(E2g + (((b << 9) + m0 + r) << 8) + kq);
    }
    __syncthreads();

    const int tl = t >> 4, tm = t & 15;   // cells: l in {tl,tl+16}, m in {tm,tm+16}
    float acc[2][2] = {};
    const f32x2 one = {1.f, 1.f};

    #pragma unroll 4
    for (int k0 = 0; k0 < 256; k0 += 4) {
        const float4 w  = *(const float4*)(wo + k0);   // uniform -> s_load
        const float4 a0 = *(const float4*)(E1s + tl * 260 + k0);
        const float4 a1 = *(const float4*)(E1s + (tl + 16) * 260 + k0);
        const float4 q0 = *(const float4*)(E2s + tm * 260 + k0);
        const float4 q1 = *(const float4*)(E2s + (tm + 16) * 260 + k0);
        pair4(a0, q0, w, one, acc[0][0]);
        pair4(a0, q1, w, one, acc[0][1]);
        pair4(a1, q0, w, one, acc[1][0]);
        pair4(a1, q1, w, one, acc[1][1]);
    }
    __syncthreads();

    // aff = -2*acc (the -2*wo factor folded); E = exp(aff), SW cancels
    affs[tl * 36 + tm]             = __builtin_amdgcn_exp2f(acc[0][0] * N2LOG2E);
    affs[tl * 36 + tm + 16]        = __builtin_amdgcn_exp2f(acc[0][1] * N2LOG2E);
    affs[(tl + 16) * 36 + tm]      = __builtin_amdgcn_exp2f(acc[1][0] * N2LOG2E);
    affs[(tl + 16) * 36 + tm + 16] = __builtin_amdgcn_exp2f(acc[1][1] * N2LOG2E);
    __syncthreads();

    const int r  = t >> 3;
    const int c4 = (t & 7) << 2;
    // natural: EN[l][m]=E*p1[l]; S1[l]+=sum_m E*p2[m]
    {
        float4 e = *(const float4*)(affs + r * 36 + c4);
        const float p1r = p1g[(b << 9) + l0 + r];
        float4 vn = make_float4(e.x * p1r, e.y * p1r, e.z * p1r, e.w * p1r);
        *(float4*)(EN + (((b << 9) + l0 + r) << 9) + m0 + c4) = vn;
        float4 p2v = *(const float4*)(p2g + (b << 9) + m0 + c4);
        float s = (e.x * p2v.x + e.y * p2v.y) + (e.z * p2v.z + e.w * p2v.w);
        s += __shfl_xor(s, 1, 64);
        s += __shfl_xor(s, 2, 64);
        s += __shfl_xor(s, 4, 64);
        if ((t & 7) == 0) atomicAdd(S1 + (b << 9) + l0 + r, s);
    }
    // transposed: ET[m][l]=E^T*p2[m]; S2[m]+=sum_l E*p1[l]
    {
        float4 te;
        te.x = affs[(c4 + 0) * 36 + r];
        te.y = affs[(c4 + 1) * 36 + r];
        te.z = affs[(c4 + 2) * 36 + r];
        te.w = affs[(c4 + 3) * 36 + r];
        const float p2r = p2g[(b << 9) + m0 + r];
        float4 vt = make_float4(te.x * p2r, te.y * p2r, te.z * p2r, te.w * p2r);
        *(float4*)(ET + (((b << 9) + m0 + r) << 9) + l0 + c4) = vt;
        float4 p1v = *(const float4*)(p1g + (b << 9) + l0 + c4);
        float s = (te.x * p1v.x + te.y * p1v.y) + (te.z * p1v.z + te.w * p1v.w);
        s += __shfl_xor(s, 1, 64);
        s += __shfl_xor(s, 2, 64);
        s += __shfl_xor(s, 4, 64);
        if ((t & 7) == 0) atomicAdd(S2 + (b << 9) + m0 + r, s);
    }
}

// --------------------------------------------------------------- k_final
__global__ __launch_bounds__(256) void k_final(
    const float* __restrict__ EN, const float* __restrict__ ET,
    const float* __restrict__ U1, const float* __restrict__ U2,
    const float* __restrict__ P12, const float* __restrict__ P21,
    const float* __restrict__ S1, const float* __restrict__ S2,
    float* __restrict__ out)
{
    const int t   = threadIdx.x;
    const int r0  = blockIdx.x * 32, n0 = blockIdx.y * 32;
    const int dir = blockIdx.z >> 1, b = blockIdx.z & 1;
    const float* Ag = (dir == 0 ? ET  : EN)  + b * 262144;  // [row][k], stride 512
    const float* Sg = (dir == 0 ? S1  : S2)  + b * 512;
    const float* Bg = (dir == 0 ? U1  : U2)  + b * 131072;  // [k][n], stride 256
    const float* Pg = (dir == 0 ? P12 : P21) + b * 131072;  // [row][n], stride 256
    float* o = out + (dir == 0 ? 262144 : 0);

    __shared__ __align__(16) short Abf[32 * 136];   // [row][k] bf16, rs folded
    __shared__ __align__(16) short Bbf[32 * 136];   // [n][k] bf16 (U^T)
    __shared__ __align__(16) float rs[512];

    for (int i = t; i < 512; i += 256)
        rs[i] = __builtin_amdgcn_rcpf(Sg[i]);

    const int w    = t >> 6;
    const int lane = t & 63;
    const int quad = lane >> 4;
    const int lr   = lane & 15;
    const int wr   = (w >> 1) << 4, wc = (w & 1) << 4;
    const int col  = n0 + wc + lr;

    float pre[4];                          // Pg epilogue prefetch
    #pragma unroll
    for (int reg = 0; reg < 4; ++reg) {
        const int m = r0 + wr + quad * 4 + reg;
        pre[reg] = Pg[(m << 8) + col];
    }
    __syncthreads();

    f32x4 acc = {};

    for (int kc = 0; kc < 512; kc += 128) {
        #pragma unroll
        for (int i = 0; i < 4; ++i) {               // A: 32 rows x 128 k, rs-scaled
            int slot = i * 256 + t;
            int r = slot >> 5, kq = (slot & 31) << 2;
            float4 v  = *(const float4*)(Ag + ((r0 + r) << 9) + kc + kq);
            float4 rv = *(const float4*)(rs + kc + kq);
            short4 s;
            s.x = f2bf(v.x * rv.x); s.y = f2bf(v.y * rv.y);
            s.z = f2bf(v.z * rv.z); s.w = f2bf(v.w * rv.w);
            *(short4*)(Abf + r * 136 + kq) = s;
        }
        #pragma unroll
        for (int i = 0; i < 4; ++i) {               // B: 128 k x 32 n -> [n][k]
            int slot = i * 256 + t;
            int bk = slot >> 3, bn4 = (slot & 7) << 2;
            float4 v = *(const float4*)(Bg + ((kc + bk) << 8) + n0 + bn4);
            Bbf[(bn4 + 0) * 136 + bk] = f2bf(v.x);
            Bbf[(bn4 + 1) * 136 + bk] = f2bf(v.y);
            Bbf[(bn4 + 2) * 136 + bk] = f2bf(v.z);
            Bbf[(bn4 + 3) * 136 + bk] = f2bf(v.w);
        }
        __syncthreads();
        #pragma unroll
        for (int s = 0; s < 4; ++s) {
            const int kb = s * 32 + quad * 8;
            bf16x8 a  = *(const bf16x8*)(Abf + (wr + lr) * 136 + kb);
            bf16x8 bb = *(const bf16x8*)(Bbf + (wc + lr) * 136 + kb);
            acc = __builtin_amdgcn_mfma_f32_16x16x32_bf16(a, bb, acc, 0, 0, 0);
        }
        __syncthreads();
    }

    #pragma unroll
    for (int reg = 0; reg < 4; ++reg) {
        const int m = r0 + wr + quad * 4 + reg;
        float v = acc[reg] + pre[reg];
        float tv = 1.f - 2.f * __builtin_amdgcn_rcpf(
                       __builtin_amdgcn_exp2f(v * TWO_LOG2E) + 1.f);
        o[((m << 1) + b) * 256 + col] = tv;
    }
}

// ---------------------------------------------------------------- launch
extern "C" void kernel_launch(void* const* d_in, const int* in_sizes, int n_in,
                              void* d_out, int out_size, void* d_ws, size_t ws_size,
                              hipStream_t stream)
{
    const float* ctx1 = (const float*)d_in[0];
    const float* ctx2 = (const float*)d_in[1];
    const float* m1   = (const float*)d_in[2];
    const float* m2   = (const float*)d_in[3];
    const float* Wh   = (const float*)d_in[4];
    const float* bh   = (const float*)d_in[5];
    const float* wo   = (const float*)d_in[6];
    const float* W12  = (const float*)d_in[7];
    const float* b12  = (const float*)d_in[8];
    const float* W21  = (const float*)d_in[9];
    const float* b21  = (const float*)d_in[10];
    float* out = (float*)d_out;
    float* ws  = (float*)d_ws;

    float* E1  = ws;                 // 262144
    float* E2  = E1  + 262144;
    float* P12 = E2  + 262144;
    float* U1  = P12 + 262144;
    float* P21 = U1  + 262144;
    float* U2  = P21 + 262144;
    float* p1  = U2  + 262144;       // 1024
    float* p2  = p1  + 1024;
    float* S1  = p2  + 1024;         // 1024
    float* S2  = S1  + 1024;
    float* EN  = S2  + 1024;         // 524288
    float* ET  = EN  + 524288;       // 524288

    hipLaunchKernelGGL(k_proj, dim3(512, 1, 1), dim3(256), 0, stream,
                       ctx1, ctx2, Wh, bh, W12, b12, W21, b21, m1, m2,
                       E1, E2, P12, U1, P21, U2, p1, p2, S1, S2);
    hipLaunchKernelGGL(k_aff, dim3(512, 1, 1), dim3(256), 0, stream,
                       E1, E2, wo, p1, p2, EN, ET, S1, S2);
    hipLaunchKernelGGL(k_final, dim3(16, 8, 4), dim3(256), 0, stream,
                       EN, ET, U1, U2, P12, P21, S1, S2, out);
}

// Round 5
// 113.332 us; speedup vs baseline: 1.0476x; 1.0476x over previous
//
#include <hip/hip_runtime.h>

// CoAttention, 3-kernel pipeline. R16 = R14 structure (best, 115.26us) +
// two pure instruction-count cuts (no grid/LDS/occupancy changes):
//  (1) f2bf via native (__bf16) cast -> v_cvt_pk_bf16_f32 pairs (RNE=RNE).
//  (2) EN/ET stored bf16 by k_aff; k_final A-staging is a raw short8 copy
//      (no cvt, no mul), 1/S folded into B-staging instead. Halves EN/ET
//      write+read bytes and cuts ~40% of k_final staging VALU.
// R15 lesson: aff single-chunk (71KB LDS, occ 4->2) + pk_fma asm regressed
// +3.5us; keep R14's 2-chunk aff + compiler-scheduled FMAs.
// Budget model: ~88us fixed (harness poison fills) + ~26us controllable.

#define NEGC (-1e12f)
#define TWO_LOG2E 2.8853900817779268f
#define LOG2E 1.4426950408889634f
#define N2LOG2E (-2.8853900817779268f)

typedef __attribute__((ext_vector_type(8))) short bf16x8;
typedef __attribute__((ext_vector_type(4))) float f32x4;

__device__ __forceinline__ short f2bf(float x)   // RNE f32->bf16 (native cvt)
{
    return __builtin_bit_cast(short, (__bf16)x);
}

// --------------------------------------------------------------- k_projE
// E1 = exp(2*(ctx1 @ Wh[:256] + bh)), E2 = exp(2*(ctx2 @ Wh[256:])).
// 32x64 tile, single K=256 chunk. grid (32,4,2).
__global__ __launch_bounds__(256) void k_projE(
    const float* __restrict__ ctx1, const float* __restrict__ ctx2,
    const float* __restrict__ Wh, const float* __restrict__ bh,
    const float* __restrict__ mask1, const float* __restrict__ mask2,
    float* __restrict__ E1, float* __restrict__ E2,
    float* __restrict__ p1, float* __restrict__ p2,
    float* __restrict__ S1, float* __restrict__ S2)
{
    const int t  = threadIdx.x;
    const int g  = blockIdx.z;
    const int r0 = blockIdx.x * 32;       // rows = l*2+b in [0,1024)
    const int n0 = blockIdx.y * 64;       // N in [0,256)

    const float* A    = g ? ctx2       : ctx1;
    const float* W    = g ? Wh + 65536 : Wh;
    const float* bias = g ? 0          : bh;
    float*       outp = g ? E2         : E1;

    if (g == 0 && blockIdx.x == 0 && blockIdx.y == 0) {
        for (int idx = t; idx < 1024; idx += 256) {
            int row = idx >> 1, b = idx & 1;
            p1[b * 512 + row] = __builtin_amdgcn_exp2f(LOG2E * (1.f - mask1[idx]) * NEGC);
            p2[b * 512 + row] = __builtin_amdgcn_exp2f(LOG2E * (1.f - mask2[idx]) * NEGC);
            S1[b * 512 + row] = 0.f;
            S2[b * 512 + row] = 0.f;
        }
    }

    __shared__ __align__(16) short Abf[32 * 264];   // [m][k] bf16, full K
    __shared__ __align__(16) short Bbf[64 * 264];   // [n][k] bf16 (W^T), full K

    #pragma unroll
    for (int i = 0; i < 8; ++i) {                   // A: 32 rows x 256 k
        int slot = i * 256 + t;
        int r = slot >> 6, kq = (slot & 63) << 2;
        float4 v = *(const float4*)(A + (r0 + r) * 256 + kq);
        short4 s; s.x = f2bf(v.x); s.y = f2bf(v.y); s.z = f2bf(v.z); s.w = f2bf(v.w);
        *(short4*)(Abf + r * 264 + kq) = s;
    }
    #pragma unroll
    for (int i = 0; i < 16; ++i) {                  // B: 256 k x 64 n -> B^T
        int slot = i * 256 + t;
        int bk = slot >> 4, bn4 = (slot & 15) << 2;
        float4 v = *(const float4*)(W + bk * 256 + n0 + bn4);
        Bbf[(bn4 + 0) * 264 + bk] = f2bf(v.x);
        Bbf[(bn4 + 1) * 264 + bk] = f2bf(v.y);
        Bbf[(bn4 + 2) * 264 + bk] = f2bf(v.z);
        Bbf[(bn4 + 3) * 264 + bk] = f2bf(v.w);
    }
    __syncthreads();

    const int w    = t >> 6;
    const int lane = t & 63;
    const int quad = lane >> 4;
    const int lr   = lane & 15;
    const int h    = w & 1;               // row-half: rows r0 + h*16 + ...
    const int c    = w >> 1;              // col-half: cols n0 + c*32 + nc*16

    f32x4 acc[2] = {};

    #pragma unroll
    for (int s = 0; s < 8; ++s) {
        const int kb = s * 32 + quad * 8;
        bf16x8 a = *(const bf16x8*)(Abf + (h * 16 + lr) * 264 + kb);
        #pragma unroll
        for (int nc = 0; nc < 2; ++nc) {
            bf16x8 b = *(const bf16x8*)(Bbf + (c * 32 + nc * 16 + lr) * 264 + kb);
            acc[nc] = __builtin_amdgcn_mfma_f32_16x16x32_bf16(a, b, acc[nc], 0, 0, 0);
        }
    }

    #pragma unroll
    for (int nc = 0; nc < 2; ++nc) {
        const int col = n0 + c * 32 + nc * 16 + lr;
        const float bv = bias ? bias[col] : 0.f;
        #pragma unroll
        for (int reg = 0; reg < 4; ++reg) {
            int row  = r0 + h * 16 + quad * 4 + reg;   // = l*2+b
            int orow = ((row & 1) << 9) + (row >> 1);
            float v = acc[nc][reg] + bv;
            outp[orow * 256 + col] = __builtin_amdgcn_exp2f(v * TWO_LOG2E);
        }
    }
}

// ---------------------------------------------------------------- k_mid
// PAIR: acc += w.x/x0 + w.y/x1 + w.z/x2 + w.w/x3 with 2 rcp via pairing.
#define PAIR(AV, QV, WV, ACC) do {                                    \
    float x0_ = fmaf(AV.x, QV.x, 1.f);                                \
    float x1_ = fmaf(AV.y, QV.y, 1.f);                                \
    float x2_ = fmaf(AV.z, QV.z, 1.f);                                \
    float x3_ = fmaf(AV.w, QV.w, 1.f);                                \
    float r01_ = __builtin_amdgcn_rcpf(x0_ * x1_);                    \
    float r23_ = __builtin_amdgcn_rcpf(x2_ * x3_);                    \
    float z01_ = fmaf(WV.y, x0_, WV.x * x1_);                         \
    float z23_ = fmaf(WV.w, x2_, WV.z * x3_);                         \
    ACC = fmaf(r01_, z01_, ACC);                                      \
    ACC = fmaf(r23_, z23_, ACC);                                      \
} while (0)

__global__ __launch_bounds__(256) void k_mid(
    const float* __restrict__ ctx1, const float* __restrict__ ctx2,
    const float* __restrict__ W12, const float* __restrict__ b12,
    const float* __restrict__ W21, const float* __restrict__ b21,
    const float* __restrict__ E1g, const float* __restrict__ E2g,
    const float* __restrict__ wo,
    const float* __restrict__ p1g, const float* __restrict__ p2g,
    float* __restrict__ P12, float* __restrict__ U1,
    float* __restrict__ P21, float* __restrict__ U2,
    short* __restrict__ EN, short* __restrict__ ET,
    float* __restrict__ S1, float* __restrict__ S2)
{
    // LDS union: aff path needs 38400 B (2x 32*132 f32 + 32*36 f32);
    // gemm path needs 34816 B (2x 64*136 bf16).
    __shared__ __align__(16) char smem[38400];

    const int t   = threadIdx.x;
    const int bid = blockIdx.x;
    const int r3  = bid % 3;

    if (r3 == 2) {
        // ---------------- GEMM path: 4 U/P projections (k_final inputs only)
        const int idx = bid / 3;              // [0,256)
        const int g   = idx >> 6;             // 64 blocks per projection
        const int r0  = (idx & 15) * 64;
        const int n0  = ((idx >> 4) & 3) * 64;

        const float* A; const float* W; const float* bias; float* outp;
        switch (g) {
          case 0:  A = ctx2; W = W12;         bias = b12; outp = P12; break;
          case 1:  A = ctx1; W = W12 + 65536; bias = 0;   outp = U1;  break;
          case 2:  A = ctx1; W = W21;         bias = b21; outp = P21; break;
          default: A = ctx2; W = W21 + 65536; bias = 0;   outp = U2;  break;
        }

        short* Abf = (short*)smem;            // [64][136]
        short* Bbf = Abf + 64 * 136;          // [64][136]

        const int w    = t >> 6;
        const int lane = t & 63;
        const int quad = lane >> 4;
        const int lr   = lane & 15;

        f32x4 acc[4] = {};

        for (int kc = 0; kc < 256; kc += 128) {
            #pragma unroll
            for (int i = 0; i < 8; ++i) {             // A: 64 rows x 128 k
                int slot = i * 256 + t;
                int r = slot >> 5, kq = (slot & 31) << 2;
                float4 v = *(const float4*)(A + (r0 + r) * 256 + kc + kq);
                short4 s; s.x = f2bf(v.x); s.y = f2bf(v.y); s.z = f2bf(v.z); s.w = f2bf(v.w);
                *(short4*)(Abf + r * 136 + kq) = s;
            }
            #pragma unroll
            for (int i = 0; i < 8; ++i) {             // B: 128 k x 64 n -> B^T
                int slot = i * 256 + t;
                int bk = slot >> 4, bn4 = (slot & 15) << 2;
                float4 v = *(const float4*)(W + (kc + bk) * 256 + n0 + bn4);
                Bbf[(bn4 + 0) * 136 + bk] = f2bf(v.x);
                Bbf[(bn4 + 1) * 136 + bk] = f2bf(v.y);
                Bbf[(bn4 + 2) * 136 + bk] = f2bf(v.z);
                Bbf[(bn4 + 3) * 136 + bk] = f2bf(v.w);
            }
            __syncthreads();
            #pragma unroll
            for (int s = 0; s < 4; ++s) {
                const int kb = s * 32 + quad * 8;
                bf16x8 a = *(const bf16x8*)(Abf + (w * 16 + lr) * 136 + kb);
                #pragma unroll
                for (int nc = 0; nc < 4; ++nc) {
                    bf16x8 b = *(const bf16x8*)(Bbf + (nc * 16 + lr) * 136 + kb);
                    acc[nc] = __builtin_amdgcn_mfma_f32_16x16x32_bf16(a, b, acc[nc], 0, 0, 0);
                }
            }
            __syncthreads();
        }

        #pragma unroll
        for (int nc = 0; nc < 4; ++nc) {
            const int col = n0 + nc * 16 + lr;
            const float bv = bias ? bias[col] : 0.f;
            #pragma unroll
            for (int reg = 0; reg < 4; ++reg) {
                int row  = r0 + w * 16 + quad * 4 + reg;   // = l*2+b
                int orow = ((row & 1) << 9) + (row >> 1);
                outp[orow * 256 + col] = acc[nc][reg] + bv;
            }
        }
    } else {
        // ---------------- affinity path (identical math to R14)
        const int aidx = (bid / 3) * 2 + r3;  // [0,512)
        const int l0 = (aidx & 15) * 32;
        const int m0 = ((aidx >> 4) & 15) * 32;
        const int b  = aidx >> 8;

        float* E1s  = (float*)smem;           // [32][132]
        float* E2s  = E1s + 32 * 132;         // [32][132]
        float* affs = E2s + 32 * 132;         // [32][36]

        const int tl = t >> 4, tm = t & 15;   // cells: l in {tl,tl+16}, m in {tm,tm+16}
        float acc[2][2] = {};

        for (int kc = 0; kc < 256; kc += 128) {
            #pragma unroll
            for (int i = 0; i < 4; ++i) {             // 32 rows x 128 k, both panels
                int slot = i * 256 + t;
                int r = slot >> 5, kq = (slot & 31) << 2;
                *(float4*)(E1s + r * 132 + kq) =
                    *(const float4*)(E1g + (((b << 9) + l0 + r) << 8) + kc + kq);
                *(float4*)(E2s + r * 132 + kq) =
                    *(const float4*)(E2g + (((b << 9) + m0 + r) << 8) + kc + kq);
            }
            __syncthreads();
            #pragma unroll 4
            for (int k0 = 0; k0 < 128; k0 += 4) {
                const float4 w  = *(const float4*)(wo + kc + k0);   // uniform -> s_load
                const float4 a0 = *(const float4*)(E1s + tl * 132 + k0);
                const float4 a1 = *(const float4*)(E1s + (tl + 16) * 132 + k0);
                const float4 q0 = *(const float4*)(E2s + tm * 132 + k0);
                const float4 q1 = *(const float4*)(E2s + (tm + 16) * 132 + k0);
                PAIR(a0, q0, w, acc[0][0]);
                PAIR(a0, q1, w, acc[0][1]);
                PAIR(a1, q0, w, acc[1][0]);
                PAIR(a1, q1, w, acc[1][1]);
            }
            __syncthreads();
        }

        // aff = -2*acc (the -2*wo factor folded); E = exp(aff), SW cancels
        affs[tl * 36 + tm]             = __builtin_amdgcn_exp2f(acc[0][0] * N2LOG2E);
        affs[tl * 36 + tm + 16]        = __builtin_amdgcn_exp2f(acc[0][1] * N2LOG2E);
        affs[(tl + 16) * 36 + tm]      = __builtin_amdgcn_exp2f(acc[1][0] * N2LOG2E);
        affs[(tl + 16) * 36 + tm + 16] = __builtin_amdgcn_exp2f(acc[1][1] * N2LOG2E);
        __syncthreads();

        const int r  = t >> 3;
        const int c4 = (t & 7) << 2;
        // natural: EN[l][m]=bf16(E*p1[l]); S1[l]+=sum_m E*p2[m]
        {
            float4 e = *(const float4*)(affs + r * 36 + c4);
            const float p1r = p1g[(b << 9) + l0 + r];
            short4 vn;
            vn.x = f2bf(e.x * p1r); vn.y = f2bf(e.y * p1r);
            vn.z = f2bf(e.z * p1r); vn.w = f2bf(e.w * p1r);
            *(short4*)(EN + (((b << 9) + l0 + r) << 9) + m0 + c4) = vn;
            float4 p2v = *(const float4*)(p2g + (b << 9) + m0 + c4);
            float s = (e.x * p2v.x + e.y * p2v.y) + (e.z * p2v.z + e.w * p2v.w);
            s += __shfl_xor(s, 1, 64);
            s += __shfl_xor(s, 2, 64);
            s += __shfl_xor(s, 4, 64);
            if ((t & 7) == 0) atomicAdd(S1 + (b << 9) + l0 + r, s);
        }
        // transposed: ET[m][l]=bf16(E^T*p2[m]); S2[m]+=sum_l E*p1[l]
        {
            float4 te;
            te.x = affs[(c4 + 0) * 36 + r];
            te.y = affs[(c4 + 1) * 36 + r];
            te.z = affs[(c4 + 2) * 36 + r];
            te.w = affs[(c4 + 3) * 36 + r];
            const float p2r = p2g[(b << 9) + m0 + r];
            short4 vt;
            vt.x = f2bf(te.x * p2r); vt.y = f2bf(te.y * p2r);
            vt.z = f2bf(te.z * p2r); vt.w = f2bf(te.w * p2r);
            *(short4*)(ET + (((b << 9) + m0 + r) << 9) + l0 + c4) = vt;
            float4 p1v = *(const float4*)(p1g + (b << 9) + l0 + c4);
            float s = (te.x * p1v.x + te.y * p1v.y) + (te.z * p1v.z + te.w * p1v.w);
            s += __shfl_xor(s, 1, 64);
            s += __shfl_xor(s, 2, 64);
            s += __shfl_xor(s, 4, 64);
            if ((t & 7) == 0) atomicAdd(S2 + (b << 9) + m0 + r, s);
        }
    }
}

// --------------------------------------------------------------- k_final
__global__ __launch_bounds__(256) void k_final(
    const short* __restrict__ EN, const short* __restrict__ ET,
    const float* __restrict__ U1, const float* __restrict__ U2,
    const float* __restrict__ P12, const float* __restrict__ P21,
    const float* __restrict__ S1, const float* __restrict__ S2,
    float* __restrict__ out)
{
    const int t   = threadIdx.x;
    const int r0  = blockIdx.x * 32, n0 = blockIdx.y * 32;
    const int dir = blockIdx.z >> 1, b = blockIdx.z & 1;
    const short* Ag = (dir == 0 ? ET  : EN)  + b * 262144;  // [row][k] bf16, stride 512
    const float* Sg = (dir == 0 ? S1  : S2)  + b * 512;
    const float* Bg = (dir == 0 ? U1  : U2)  + b * 131072;  // [k][n], stride 256
    const float* Pg = (dir == 0 ? P12 : P21) + b * 131072;  // [row][n], stride 256
    float* o = out + (dir == 0 ? 262144 : 0);

    __shared__ __align__(16) short Abf[32 * 136];   // [row][k] bf16 (raw copy)
    __shared__ __align__(16) short Bbf[32 * 136];   // [n][k] bf16 (U^T, rs folded)
    __shared__ __align__(16) float rs[512];

    for (int i = t; i < 512; i += 256)
        rs[i] = __builtin_amdgcn_rcpf(Sg[i]);

    const int w    = t >> 6;
    const int lane = t & 63;
    const int quad = lane >> 4;
    const int lr   = lane & 15;
    const int wr   = (w >> 1) << 4, wc = (w & 1) << 4;
    const int col  = n0 + wc + lr;

    float pre[4];                          // Pg epilogue prefetch
    #pragma unroll
    for (int reg = 0; reg < 4; ++reg) {
        const int m = r0 + wr + quad * 4 + reg;
        pre[reg] = Pg[(m << 8) + col];
    }
    __syncthreads();

    f32x4 acc = {};

    for (int kc = 0; kc < 512; kc += 128) {
        #pragma unroll
        for (int i = 0; i < 2; ++i) {               // A: 32 rows x 128 k, raw bf16 copy
            int slot = i * 256 + t;                 // 512 short8 slots
            int r = slot >> 4, k8 = (slot & 15) << 3;
            *(bf16x8*)(Abf + r * 136 + k8) =
                *(const bf16x8*)(Ag + ((r0 + r) << 9) + kc + k8);
        }
        #pragma unroll
        for (int i = 0; i < 4; ++i) {               // B: 128 k x 32 n -> [n][k], rs folded
            int slot = i * 256 + t;
            int bk = slot >> 3, bn4 = (slot & 7) << 2;
            float4 v = *(const float4*)(Bg + ((kc + bk) << 8) + n0 + bn4);
            const float rsv = rs[kc + bk];
            Bbf[(bn4 + 0) * 136 + bk] = f2bf(v.x * rsv);
            Bbf[(bn4 + 1) * 136 + bk] = f2bf(v.y * rsv);
            Bbf[(bn4 + 2) * 136 + bk] = f2bf(v.z * rsv);
            Bbf[(bn4 + 3) * 136 + bk] = f2bf(v.w * rsv);
        }
        __syncthreads();
        #pragma unroll
        for (int s = 0; s < 4; ++s) {
            const int kb = s * 32 + quad * 8;
            bf16x8 a  = *(const bf16x8*)(Abf + (wr + lr) * 136 + kb);
            bf16x8 bb = *(const bf16x8*)(Bbf + (wc + lr) * 136 + kb);
            acc = __builtin_amdgcn_mfma_f32_16x16x32_bf16(a, bb, acc, 0, 0, 0);
        }
        __syncthreads();
    }

    #pragma unroll
    for (int reg = 0; reg < 4; ++reg) {
        const int m = r0 + wr + quad * 4 + reg;
        float v = acc[reg] + pre[reg];
        float tv = 1.f - 2.f * __builtin_amdgcn_rcpf(
                       __builtin_amdgcn_exp2f(v * TWO_LOG2E) + 1.f);
        o[((m << 1) + b) * 256 + col] = tv;
    }
}

// ---------------------------------------------------------------- launch
extern "C" void kernel_launch(void* const* d_in, const int* in_sizes, int n_in,
                              void* d_out, int out_size, void* d_ws, size_t ws_size,
                              hipStream_t stream)
{
    const float* ctx1 = (const float*)d_in[0];
    const float* ctx2 = (const float*)d_in[1];
    const float* m1   = (const float*)d_in[2];
    const float* m2   = (const float*)d_in[3];
    const float* Wh   = (const float*)d_in[4];
    const float* bh   = (const float*)d_in[5];
    const float* wo   = (const float*)d_in[6];
    const float* W12  = (const float*)d_in[7];
    const float* b12  = (const float*)d_in[8];
    const float* W21  = (const float*)d_in[9];
    const float* b21  = (const float*)d_in[10];
    float* out = (float*)d_out;
    float* ws  = (float*)d_ws;

    float* E1  = ws;                 // 262144
    float* E2  = E1  + 262144;
    float* P12 = E2  + 262144;
    float* U1  = P12 + 262144;
    float* P21 = U1  + 262144;
    float* U2  = P21 + 262144;
    float* p1  = U2  + 262144;       // 1024
    float* p2  = p1  + 1024;
    float* S1  = p2  + 1024;         // 1024
    float* S2  = S1  + 1024;
    float* ENf = S2  + 1024;         // 524288 floats reserved
    float* ETf = ENf + 524288;       // 524288 floats reserved
    short* EN16 = (short*)ENf;       // [2][512][512] bf16
    short* ET16 = (short*)ETf;       // [2][512][512] bf16

    hipLaunchKernelGGL(k_projE, dim3(32, 4, 2), dim3(256), 0, stream,
                       ctx1, ctx2, Wh, bh, m1, m2, E1, E2, p1, p2, S1, S2);
    hipLaunchKernelGGL(k_mid, dim3(768, 1, 1), dim3(256), 0, stream,
                       ctx1, ctx2, W12, b12, W21, b21,
                       E1, E2, wo, p1, p2,
                       P12, U1, P21, U2, EN16, ET16, S1, S2);
    hipLaunchKernelGGL(k_final, dim3(16, 8, 4), dim3(256), 0, stream,
                       EN16, ET16, U1, U2, P12, P21, S1, S2, out);
}

// Round 6
// 106.850 us; speedup vs baseline: 1.1111x; 1.0607x over previous
//
#include <hip/hip_runtime.h>

// CoAttention, 3-kernel pipeline. R17 = R16 (113.33us) + k_final LDS
// double-buffer (ONLY change):
//  k_final: 2x (Abf,Bbf) ping-pong, fully unrolled 4-chunk K loop.
//           Barriers 9 -> 5; chunk c+1 global loads overlap chunk c MFMA.
//           LDS 19.4 -> 37 KB (grid 2 blocks/CU, no occupancy change).
// R16 carried: native (__bf16) cvt everywhere; EN/ET bf16 (A raw-copy
// staging, 1/S folded into B). R15 lesson: don't touch k_mid aff structure
// (2-chunk, 38.4KB, 3/CU) or hand-pack FMAs.
// Budget model: ~88us fixed (harness poison fills @ 76-80% HBM peak) +
// ~25us controllable; aff VALU floor ~5.1us, projE ~2, final ~3.5, gaps ~4.

#define NEGC (-1e12f)
#define TWO_LOG2E 2.8853900817779268f
#define LOG2E 1.4426950408889634f
#define N2LOG2E (-2.8853900817779268f)

typedef __attribute__((ext_vector_type(8))) short bf16x8;
typedef __attribute__((ext_vector_type(4))) float f32x4;

__device__ __forceinline__ short f2bf(float x)   // RNE f32->bf16 (native cvt)
{
    return __builtin_bit_cast(short, (__bf16)x);
}

// --------------------------------------------------------------- k_projE
// E1 = exp(2*(ctx1 @ Wh[:256] + bh)), E2 = exp(2*(ctx2 @ Wh[256:])).
// 32x64 tile, single K=256 chunk. grid (32,4,2).
__global__ __launch_bounds__(256) void k_projE(
    const float* __restrict__ ctx1, const float* __restrict__ ctx2,
    const float* __restrict__ Wh, const float* __restrict__ bh,
    const float* __restrict__ mask1, const float* __restrict__ mask2,
    float* __restrict__ E1, float* __restrict__ E2,
    float* __restrict__ p1, float* __restrict__ p2,
    float* __restrict__ S1, float* __restrict__ S2)
{
    const int t  = threadIdx.x;
    const int g  = blockIdx.z;
    const int r0 = blockIdx.x * 32;       // rows = l*2+b in [0,1024)
    const int n0 = blockIdx.y * 64;       // N in [0,256)

    const float* A    = g ? ctx2       : ctx1;
    const float* W    = g ? Wh + 65536 : Wh;
    const float* bias = g ? 0          : bh;
    float*       outp = g ? E2         : E1;

    if (g == 0 && blockIdx.x == 0 && blockIdx.y == 0) {
        for (int idx = t; idx < 1024; idx += 256) {
            int row = idx >> 1, b = idx & 1;
            p1[b * 512 + row] = __builtin_amdgcn_exp2f(LOG2E * (1.f - mask1[idx]) * NEGC);
            p2[b * 512 + row] = __builtin_amdgcn_exp2f(LOG2E * (1.f - mask2[idx]) * NEGC);
            S1[b * 512 + row] = 0.f;
            S2[b * 512 + row] = 0.f;
        }
    }

    __shared__ __align__(16) short Abf[32 * 264];   // [m][k] bf16, full K
    __shared__ __align__(16) short Bbf[64 * 264];   // [n][k] bf16 (W^T), full K

    #pragma unroll
    for (int i = 0; i < 8; ++i) {                   // A: 32 rows x 256 k
        int slot = i * 256 + t;
        int r = slot >> 6, kq = (slot & 63) << 2;
        float4 v = *(const float4*)(A + (r0 + r) * 256 + kq);
        short4 s; s.x = f2bf(v.x); s.y = f2bf(v.y); s.z = f2bf(v.z); s.w = f2bf(v.w);
        *(short4*)(Abf + r * 264 + kq) = s;
    }
    #pragma unroll
    for (int i = 0; i < 16; ++i) {                  // B: 256 k x 64 n -> B^T
        int slot = i * 256 + t;
        int bk = slot >> 4, bn4 = (slot & 15) << 2;
        float4 v = *(const float4*)(W + bk * 256 + n0 + bn4);
        Bbf[(bn4 + 0) * 264 + bk] = f2bf(v.x);
        Bbf[(bn4 + 1) * 264 + bk] = f2bf(v.y);
        Bbf[(bn4 + 2) * 264 + bk] = f2bf(v.z);
        Bbf[(bn4 + 3) * 264 + bk] = f2bf(v.w);
    }
    __syncthreads();

    const int w    = t >> 6;
    const int lane = t & 63;
    const int quad = lane >> 4;
    const int lr   = lane & 15;
    const int h    = w & 1;               // row-half: rows r0 + h*16 + ...
    const int c    = w >> 1;              // col-half: cols n0 + c*32 + nc*16

    f32x4 acc[2] = {};

    #pragma unroll
    for (int s = 0; s < 8; ++s) {
        const int kb = s * 32 + quad * 8;
        bf16x8 a = *(const bf16x8*)(Abf + (h * 16 + lr) * 264 + kb);
        #pragma unroll
        for (int nc = 0; nc < 2; ++nc) {
            bf16x8 b = *(const bf16x8*)(Bbf + (c * 32 + nc * 16 + lr) * 264 + kb);
            acc[nc] = __builtin_amdgcn_mfma_f32_16x16x32_bf16(a, b, acc[nc], 0, 0, 0);
        }
    }

    #pragma unroll
    for (int nc = 0; nc < 2; ++nc) {
        const int col = n0 + c * 32 + nc * 16 + lr;
        const float bv = bias ? bias[col] : 0.f;
        #pragma unroll
        for (int reg = 0; reg < 4; ++reg) {
            int row  = r0 + h * 16 + quad * 4 + reg;   // = l*2+b
            int orow = ((row & 1) << 9) + (row >> 1);
            float v = acc[nc][reg] + bv;
            outp[orow * 256 + col] = __builtin_amdgcn_exp2f(v * TWO_LOG2E);
        }
    }
}

// ---------------------------------------------------------------- k_mid
// PAIR: acc += w.x/x0 + w.y/x1 + w.z/x2 + w.w/x3 with 2 rcp via pairing.
#define PAIR(AV, QV, WV, ACC) do {                                    \
    float x0_ = fmaf(AV.x, QV.x, 1.f);                                \
    float x1_ = fmaf(AV.y, QV.y, 1.f);                                \
    float x2_ = fmaf(AV.z, QV.z, 1.f);                                \
    float x3_ = fmaf(AV.w, QV.w, 1.f);                                \
    float r01_ = __builtin_amdgcn_rcpf(x0_ * x1_);                    \
    float r23_ = __builtin_amdgcn_rcpf(x2_ * x3_);                    \
    float z01_ = fmaf(WV.y, x0_, WV.x * x1_);                         \
    float z23_ = fmaf(WV.w, x2_, WV.z * x3_);                         \
    ACC = fmaf(r01_, z01_, ACC);                                      \
    ACC = fmaf(r23_, z23_, ACC);                                      \
} while (0)

__global__ __launch_bounds__(256) void k_mid(
    const float* __restrict__ ctx1, const float* __restrict__ ctx2,
    const float* __restrict__ W12, const float* __restrict__ b12,
    const float* __restrict__ W21, const float* __restrict__ b21,
    const float* __restrict__ E1g, const float* __restrict__ E2g,
    const float* __restrict__ wo,
    const float* __restrict__ p1g, const float* __restrict__ p2g,
    float* __restrict__ P12, float* __restrict__ U1,
    float* __restrict__ P21, float* __restrict__ U2,
    short* __restrict__ EN, short* __restrict__ ET,
    float* __restrict__ S1, float* __restrict__ S2)
{
    // LDS union: aff path needs 38400 B (2x 32*132 f32 + 32*36 f32);
    // gemm path needs 34816 B (2x 64*136 bf16).
    __shared__ __align__(16) char smem[38400];

    const int t   = threadIdx.x;
    const int bid = blockIdx.x;
    const int r3  = bid % 3;

    if (r3 == 2) {
        // ---------------- GEMM path: 4 U/P projections (k_final inputs only)
        const int idx = bid / 3;              // [0,256)
        const int g   = idx >> 6;             // 64 blocks per projection
        const int r0  = (idx & 15) * 64;
        const int n0  = ((idx >> 4) & 3) * 64;

        const float* A; const float* W; const float* bias; float* outp;
        switch (g) {
          case 0:  A = ctx2; W = W12;         bias = b12; outp = P12; break;
          case 1:  A = ctx1; W = W12 + 65536; bias = 0;   outp = U1;  break;
          case 2:  A = ctx1; W = W21;         bias = b21; outp = P21; break;
          default: A = ctx2; W = W21 + 65536; bias = 0;   outp = U2;  break;
        }

        short* Abf = (short*)smem;            // [64][136]
        short* Bbf = Abf + 64 * 136;          // [64][136]

        const int w    = t >> 6;
        const int lane = t & 63;
        const int quad = lane >> 4;
        const int lr   = lane & 15;

        f32x4 acc[4] = {};

        for (int kc = 0; kc < 256; kc += 128) {
            #pragma unroll
            for (int i = 0; i < 8; ++i) {             // A: 64 rows x 128 k
                int slot = i * 256 + t;
                int r = slot >> 5, kq = (slot & 31) << 2;
                float4 v = *(const float4*)(A + (r0 + r) * 256 + kc + kq);
                short4 s; s.x = f2bf(v.x); s.y = f2bf(v.y); s.z = f2bf(v.z); s.w = f2bf(v.w);
                *(short4*)(Abf + r * 136 + kq) = s;
            }
            #pragma unroll
            for (int i = 0; i < 8; ++i) {             // B: 128 k x 64 n -> B^T
                int slot = i * 256 + t;
                int bk = slot >> 4, bn4 = (slot & 15) << 2;
                float4 v = *(const float4*)(W + (kc + bk) * 256 + n0 + bn4);
                Bbf[(bn4 + 0) * 136 + bk] = f2bf(v.x);
                Bbf[(bn4 + 1) * 136 + bk] = f2bf(v.y);
                Bbf[(bn4 + 2) * 136 + bk] = f2bf(v.z);
                Bbf[(bn4 + 3) * 136 + bk] = f2bf(v.w);
            }
            __syncthreads();
            #pragma unroll
            for (int s = 0; s < 4; ++s) {
                const int kb = s * 32 + quad * 8;
                bf16x8 a = *(const bf16x8*)(Abf + (w * 16 + lr) * 136 + kb);
                #pragma unroll
                for (int nc = 0; nc < 4; ++nc) {
                    bf16x8 b = *(const bf16x8*)(Bbf + (nc * 16 + lr) * 136 + kb);
                    acc[nc] = __builtin_amdgcn_mfma_f32_16x16x32_bf16(a, b, acc[nc], 0, 0, 0);
                }
            }
            __syncthreads();
        }

        #pragma unroll
        for (int nc = 0; nc < 4; ++nc) {
            const int col = n0 + nc * 16 + lr;
            const float bv = bias ? bias[col] : 0.f;
            #pragma unroll
            for (int reg = 0; reg < 4; ++reg) {
                int row  = r0 + w * 16 + quad * 4 + reg;   // = l*2+b
                int orow = ((row & 1) << 9) + (row >> 1);
                outp[orow * 256 + col] = acc[nc][reg] + bv;
            }
        }
    } else {
        // ---------------- affinity path (identical math to R14)
        const int aidx = (bid / 3) * 2 + r3;  // [0,512)
        const int l0 = (aidx & 15) * 32;
        const int m0 = ((aidx >> 4) & 15) * 32;
        const int b  = aidx >> 8;

        float* E1s  = (float*)smem;           // [32][132]
        float* E2s  = E1s + 32 * 132;         // [32][132]
        float* affs = E2s + 32 * 132;         // [32][36]

        const int tl = t >> 4, tm = t & 15;   // cells: l in {tl,tl+16}, m in {tm,tm+16}
        float acc[2][2] = {};

        for (int kc = 0; kc < 256; kc += 128) {
            #pragma unroll
            for (int i = 0; i < 4; ++i) {             // 32 rows x 128 k, both panels
                int slot = i * 256 + t;
                int r = slot >> 5, kq = (slot & 31) << 2;
                *(float4*)(E1s + r * 132 + kq) =
                    *(const float4*)(E1g + (((b << 9) + l0 + r) << 8) + kc + kq);
                *(float4*)(E2s + r * 132 + kq) =
                    *(const float4*)(E2g + (((b << 9) + m0 + r) << 8) + kc + kq);
            }
            __syncthreads();
            #pragma unroll 4
            for (int k0 = 0; k0 < 128; k0 += 4) {
                const float4 w  = *(const float4*)(wo + kc + k0);   // uniform -> s_load
                const float4 a0 = *(const float4*)(E1s + tl * 132 + k0);
                const float4 a1 = *(const float4*)(E1s + (tl + 16) * 132 + k0);
                const float4 q0 = *(const float4*)(E2s + tm * 132 + k0);
                const float4 q1 = *(const float4*)(E2s + (tm + 16) * 132 + k0);
                PAIR(a0, q0, w, acc[0][0]);
                PAIR(a0, q1, w, acc[0][1]);
                PAIR(a1, q0, w, acc[1][0]);
                PAIR(a1, q1, w, acc[1][1]);
            }
            __syncthreads();
        }

        // aff = -2*acc (the -2*wo factor folded); E = exp(aff), SW cancels
        affs[tl * 36 + tm]             = __builtin_amdgcn_exp2f(acc[0][0] * N2LOG2E);
        affs[tl * 36 + tm + 16]        = __builtin_amdgcn_exp2f(acc[0][1] * N2LOG2E);
        affs[(tl + 16) * 36 + tm]      = __builtin_amdgcn_exp2f(acc[1][0] * N2LOG2E);
        affs[(tl + 16) * 36 + tm + 16] = __builtin_amdgcn_exp2f(acc[1][1] * N2LOG2E);
        __syncthreads();

        const int r  = t >> 3;
        const int c4 = (t & 7) << 2;
        // natural: EN[l][m]=bf16(E*p1[l]); S1[l]+=sum_m E*p2[m]
        {
            float4 e = *(const float4*)(affs + r * 36 + c4);
            const float p1r = p1g[(b << 9) + l0 + r];
            short4 vn;
            vn.x = f2bf(e.x * p1r); vn.y = f2bf(e.y * p1r);
            vn.z = f2bf(e.z * p1r); vn.w = f2bf(e.w * p1r);
            *(short4*)(EN + (((b << 9) + l0 + r) << 9) + m0 + c4) = vn;
            float4 p2v = *(const float4*)(p2g + (b << 9) + m0 + c4);
            float s = (e.x * p2v.x + e.y * p2v.y) + (e.z * p2v.z + e.w * p2v.w);
            s += __shfl_xor(s, 1, 64);
            s += __shfl_xor(s, 2, 64);
            s += __shfl_xor(s, 4, 64);
            if ((t & 7) == 0) atomicAdd(S1 + (b << 9) + l0 + r, s);
        }
        // transposed: ET[m][l]=bf16(E^T*p2[m]); S2[m]+=sum_l E*p1[l]
        {
            float4 te;
            te.x = affs[(c4 + 0) * 36 + r];
            te.y = affs[(c4 + 1) * 36 + r];
            te.z = affs[(c4 + 2) * 36 + r];
            te.w = affs[(c4 + 3) * 36 + r];
            const float p2r = p2g[(b << 9) + m0 + r];
            short4 vt;
            vt.x = f2bf(te.x * p2r); vt.y = f2bf(te.y * p2r);
            vt.z = f2bf(te.z * p2r); vt.w = f2bf(te.w * p2r);
            *(short4*)(ET + (((b << 9) + m0 + r) << 9) + l0 + c4) = vt;
            float4 p1v = *(const float4*)(p1g + (b << 9) + l0 + c4);
            float s = (te.x * p1v.x + te.y * p1v.y) + (te.z * p1v.z + te.w * p1v.w);
            s += __shfl_xor(s, 1, 64);
            s += __shfl_xor(s, 2, 64);
            s += __shfl_xor(s, 4, 64);
            if ((t & 7) == 0) atomicAdd(S2 + (b << 9) + m0 + r, s);
        }
    }
}

// --------------------------------------------------------------- k_final
// Double-buffered LDS: stage chunk c+1 overlaps MFMA on chunk c.
// Barriers: 9 -> 5. All indices static (full unroll).
__global__ __launch_bounds__(256) void k_final(
    const short* __restrict__ EN, const short* __restrict__ ET,
    const float* __restrict__ U1, const float* __restrict__ U2,
    const float* __restrict__ P12, const float* __restrict__ P21,
    const float* __restrict__ S1, const float* __restrict__ S2,
    float* __restrict__ out)
{
    const int t   = threadIdx.x;
    const int r0  = blockIdx.x * 32, n0 = blockIdx.y * 32;
    const int dir = blockIdx.z >> 1, b = blockIdx.z & 1;
    const short* Ag = (dir == 0 ? ET  : EN)  + b * 262144;  // [row][k] bf16, stride 512
    const float* Sg = (dir == 0 ? S1  : S2)  + b * 512;
    const float* Bg = (dir == 0 ? U1  : U2)  + b * 131072;  // [k][n], stride 256
    const float* Pg = (dir == 0 ? P12 : P21) + b * 131072;  // [row][n], stride 256
    float* o = out + (dir == 0 ? 262144 : 0);

    __shared__ __align__(16) short Abf0[32 * 136];  // ping
    __shared__ __align__(16) short Bbf0[32 * 136];
    __shared__ __align__(16) short Abf1[32 * 136];  // pong
    __shared__ __align__(16) short Bbf1[32 * 136];
    __shared__ __align__(16) float rs[512];

    for (int i = t; i < 512; i += 256)
        rs[i] = __builtin_amdgcn_rcpf(Sg[i]);

    const int w    = t >> 6;
    const int lane = t & 63;
    const int quad = lane >> 4;
    const int lr   = lane & 15;
    const int wr   = (w >> 1) << 4, wc = (w & 1) << 4;
    const int col  = n0 + wc + lr;

    float pre[4];                          // Pg epilogue prefetch
    #pragma unroll
    for (int reg = 0; reg < 4; ++reg) {
        const int m = r0 + wr + quad * 4 + reg;
        pre[reg] = Pg[(m << 8) + col];
    }
    __syncthreads();                       // rs visible

    f32x4 acc = {};

#define STAGE(Ab, Bb, kc) do {                                            \
    _Pragma("unroll")                                                     \
    for (int i = 0; i < 2; ++i) {              /* A: raw bf16 copy */     \
        int slot = i * 256 + t;                                           \
        int r = slot >> 4, k8 = (slot & 15) << 3;                         \
        *(bf16x8*)((Ab) + r * 136 + k8) =                                 \
            *(const bf16x8*)(Ag + ((r0 + r) << 9) + (kc) + k8);           \
    }                                                                     \
    _Pragma("unroll")                                                     \
    for (int i = 0; i < 4; ++i) {              /* B: rs folded */         \
        int slot = i * 256 + t;                                           \
        int bk = slot >> 3, bn4 = (slot & 7) << 2;                        \
        float4 v = *(const float4*)(Bg + (((kc) + bk) << 8) + n0 + bn4);  \
        const float rsv = rs[(kc) + bk];                                  \
        (Bb)[(bn4 + 0) * 136 + bk] = f2bf(v.x * rsv);                     \
        (Bb)[(bn4 + 1) * 136 + bk] = f2bf(v.y * rsv);                     \
        (Bb)[(bn4 + 2) * 136 + bk] = f2bf(v.z * rsv);                     \
        (Bb)[(bn4 + 3) * 136 + bk] = f2bf(v.w * rsv);                     \
    }                                                                     \
} while (0)

#define COMPUTE(Ab, Bb) do {                                              \
    _Pragma("unroll")                                                     \
    for (int s = 0; s < 4; ++s) {                                         \
        const int kb = s * 32 + quad * 8;                                 \
        bf16x8 a_  = *(const bf16x8*)((Ab) + (wr + lr) * 136 + kb);       \
        bf16x8 bb_ = *(const bf16x8*)((Bb) + (wc + lr) * 136 + kb);       \
        acc = __builtin_amdgcn_mfma_f32_16x16x32_bf16(a_, bb_, acc, 0, 0, 0); \
    }                                                                     \
} while (0)

    STAGE(Abf0, Bbf0, 0);
    __syncthreads();                       // buf0 ready
    STAGE(Abf1, Bbf1, 128);                // overlap with compute(0)
    COMPUTE(Abf0, Bbf0);
    __syncthreads();                       // buf1 ready, buf0 reads done
    STAGE(Abf0, Bbf0, 256);
    COMPUTE(Abf1, Bbf1);
    __syncthreads();
    STAGE(Abf1, Bbf1, 384);
    COMPUTE(Abf0, Bbf0);
    __syncthreads();
    COMPUTE(Abf1, Bbf1);

#undef STAGE
#undef COMPUTE

    #pragma unroll
    for (int reg = 0; reg < 4; ++reg) {
        const int m = r0 + wr + quad * 4 + reg;
        float v = acc[reg] + pre[reg];
        float tv = 1.f - 2.f * __builtin_amdgcn_rcpf(
                       __builtin_amdgcn_exp2f(v * TWO_LOG2E) + 1.f);
        o[((m << 1) + b) * 256 + col] = tv;
    }
}

// ---------------------------------------------------------------- launch
extern "C" void kernel_launch(void* const* d_in, const int* in_sizes, int n_in,
                              void* d_out, int out_size, void* d_ws, size_t ws_size,
                              hipStream_t stream)
{
    const float* ctx1 = (const float*)d_in[0];
    const float* ctx2 = (const float*)d_in[1];
    const float* m1   = (const float*)d_in[2];
    const float* m2   = (const float*)d_in[3];
    const float* Wh   = (const float*)d_in[4];
    const float* bh   = (const float*)d_in[5];
    const float* wo   = (const float*)d_in[6];
    const float* W12  = (const float*)d_in[7];
    const float* b12  = (const float*)d_in[8];
    const float* W21  = (const float*)d_in[9];
    const float* b21  = (const float*)d_in[10];
    float* out = (float*)d_out;
    float* ws  = (float*)d_ws;

    float* E1  = ws;                 // 262144
    float* E2  = E1  + 262144;
    float* P12 = E2  + 262144;
    float* U1  = P12 + 262144;
    float* P21 = U1  + 262144;
    float* U2  = P21 + 262144;
    float* p1  = U2  + 262144;       // 1024
    float* p2  = p1  + 1024;
    float* S1  = p2  + 1024;         // 1024
    float* S2  = S1  + 1024;
    float* ENf = S2  + 1024;         // 524288 floats reserved
    float* ETf = ENf + 524288;       // 524288 floats reserved
    short* EN16 = (short*)ENf;       // [2][512][512] bf16
    short* ET16 = (short*)ETf;       // [2][512][512] bf16

    hipLaunchKernelGGL(k_projE, dim3(32, 4, 2), dim3(256), 0, stream,
                       ctx1, ctx2, Wh, bh, m1, m2, E1, E2, p1, p2, S1, S2);
    hipLaunchKernelGGL(k_mid, dim3(768, 1, 1), dim3(256), 0, stream,
                       ctx1, ctx2, W12, b12, W21, b21,
                       E1, E2, wo, p1, p2,
                       P12, U1, P21, U2, EN16, ET16, S1, S2);
    hipLaunchKernelGGL(k_final, dim3(16, 8, 4), dim3(256), 0, stream,
                       EN16, ET16, U1, U2, P12, P21, S1, S2, out);
}